// Round 6
// baseline (470.437 us; speedup 1.0000x reference)
//
#include <hip/hip_runtime.h>

#define LQ     22500
#define SPA_H  58
#define SPA_W  100
#define S_TOT  5800
#define NCAMS  6
#define CDIM   256

typedef __attribute__((ext_vector_type(8))) _Float16 half8;
typedef __attribute__((ext_vector_type(4))) _Float16 half4;
typedef __attribute__((ext_vector_type(4))) float f32x4;

__device__ __forceinline__ half8 cvt8(f32x4 lo, f32x4 hi) {
  half8 r;
  r[0] = (_Float16)lo.x; r[1] = (_Float16)lo.y; r[2] = (_Float16)lo.z; r[3] = (_Float16)lo.w;
  r[4] = (_Float16)hi.x; r[5] = (_Float16)hi.y; r[6] = (_Float16)hi.z; r[7] = (_Float16)hi.w;
  return r;
}

// ---- tiny weight conversion: W_val | W_off | W_attn | W_out -> f16 in ws ----
__global__ __launch_bounds__(256) void cvt_w(
    const float* __restrict__ W_val, const float* __restrict__ W_off,
    const float* __restrict__ W_attn, const float* __restrict__ W_out,
    _Float16* __restrict__ Wv, _Float16* __restrict__ Wcat,
    _Float16* __restrict__ Wo) {
  const int e = (blockIdx.x * 256 + threadIdx.x) * 4;
  const float* src; _Float16* dst; int off;
  if (e < 65536)       { src = W_val;  dst = Wv;   off = e; }
  else if (e < 98304)  { src = W_off;  dst = Wcat; off = e - 65536; }
  else if (e < 114688) { src = W_attn; dst = Wcat + 32768; off = e - 98304; }
  else if (e < 180224) { src = W_out;  dst = Wo;   off = e - 114688; }
  else return;
  f32x4 v = *(const f32x4*)(src + off);
  half4 o;
  o[0] = (_Float16)v.x; o[1] = (_Float16)v.y; o[2] = (_Float16)v.z; o[3] = (_Float16)v.w;
  // dst offset: W_attn case writes at Wcat+32768+(e-98304) == Wcat+(e-65536)
  *(half4*)(dst + off) = o;
}

// ---- GEMM, A = f32 (inline cvt): C[M x N] = A[M x 256] @ W[N x 256]^T + b --
// 64-row tile, 4 waves own disjoint col ranges, reg ping-pong K-loop.
template<int N>
__device__ __forceinline__ void gemm_body_af32(
    const float* __restrict__ A, const _Float16* __restrict__ W,
    const float* __restrict__ bias, const float* __restrict__ bias2,
    _Float16* __restrict__ C, int M, int rowbase) {
  constexpr int NT = N / 64;
  const int lane = threadIdx.x & 63;
  const int wave = threadIdx.x >> 6;
  const int m15  = lane & 15;
  const int quad = lane >> 4;
  const int colbase = wave * (N / 4);
  const int kq = quad * 8;

  const float* ap[4];
#pragma unroll
  for (int rt = 0; rt < 4; ++rt) {
    int r = rowbase + rt * 16 + m15;
    r = r < M ? r : M - 1;
    ap[rt] = A + (size_t)r * 256 + kq;
  }
  const _Float16* wp[NT];
#pragma unroll
  for (int t = 0; t < NT; ++t)
    wp[t] = W + (size_t)(colbase + t * 16 + m15) * 256 + kq;

  f32x4 acc[4][NT];
#pragma unroll
  for (int rt = 0; rt < 4; ++rt)
#pragma unroll
    for (int t = 0; t < NT; ++t) acc[rt][t] = (f32x4){0.f, 0.f, 0.f, 0.f};

  f32x4 al0[4], ah0[4], al1[4], ah1[4];
  half8 b0[NT], b1[NT];

#define LOADSET(AL, AH, BB, KO) \
  { _Pragma("unroll") for (int rt = 0; rt < 4; ++rt) { \
      AL[rt] = *(const f32x4*)(ap[rt] + (KO)); \
      AH[rt] = *(const f32x4*)(ap[rt] + (KO) + 4); } \
    _Pragma("unroll") for (int t = 0; t < NT; ++t) \
      BB[t] = *(const half8*)(wp[t] + (KO)); }
#define MFMASET(AL, AH, BB) \
  { half8 af[4]; \
    _Pragma("unroll") for (int rt = 0; rt < 4; ++rt) af[rt] = cvt8(AL[rt], AH[rt]); \
    _Pragma("unroll") for (int t = 0; t < NT; ++t) \
      _Pragma("unroll") for (int rt = 0; rt < 4; ++rt) \
        acc[rt][t] = __builtin_amdgcn_mfma_f32_16x16x32_f16(af[rt], BB[t], acc[rt][t], 0, 0, 0); }

  LOADSET(al0, ah0, b0, 0)
#pragma unroll 1
  for (int kk = 0; kk < 192; kk += 64) {
    LOADSET(al1, ah1, b1, kk + 32)
    MFMASET(al0, ah0, b0)
    LOADSET(al0, ah0, b0, kk + 64)
    MFMASET(al1, ah1, b1)
  }
  LOADSET(al1, ah1, b1, 224)
  MFMASET(al0, ah0, b0)
  MFMASET(al1, ah1, b1)
#undef LOADSET
#undef MFMASET

#pragma unroll
  for (int rt = 0; rt < 4; ++rt) {
    const int orow = rowbase + rt * 16 + quad * 4;
#pragma unroll
    for (int t = 0; t < NT; ++t) {
      const int col = colbase + t * 16 + m15;
      const float bv = (N == 192 && col >= 128) ? bias2[col - 128] : bias[col];
#pragma unroll
      for (int i = 0; i < 4; ++i) {
        const int r = orow + i;
        if (r < M) C[(size_t)r * 256 + col] = (_Float16)(acc[rt][t][i] + bv);
      }
    }
  }
}

// blocks [0,544): value-proj (N=256). [544,896): query-proj (N=192).
__global__ __launch_bounds__(256, 2) void gemm_inputs(
    const float* __restrict__ value, const float* __restrict__ query,
    const _Float16* __restrict__ Wv, const _Float16* __restrict__ Wcat,
    const float* __restrict__ b_val, const float* __restrict__ b_off,
    const float* __restrict__ b_attn,
    _Float16* __restrict__ vp, _Float16* __restrict__ qproj) {
  const int b = blockIdx.x;
  if (b < 544) gemm_body_af32<256>(value, Wv, b_val, b_val, vp, 34800, b * 64);
  else         gemm_body_af32<192>(query, Wcat, b_off, b_attn, qproj, LQ, (b - 544) * 64);
}

// ---- output GEMM, A = f16 slots, out f32 ----
__global__ __launch_bounds__(256, 2) void gemm_out_k(
    const _Float16* __restrict__ A, const _Float16* __restrict__ W,
    const float* __restrict__ bias, float* __restrict__ out) {
  constexpr int NT = 4;
  const int lane = threadIdx.x & 63;
  const int wave = threadIdx.x >> 6;
  const int m15  = lane & 15;
  const int quad = lane >> 4;
  const int rowbase = blockIdx.x * 64;
  const int colbase = wave * 64;
  const int kq = quad * 8;

  const _Float16* ap[4];
#pragma unroll
  for (int rt = 0; rt < 4; ++rt) {
    int r = rowbase + rt * 16 + m15;
    r = r < LQ ? r : LQ - 1;
    ap[rt] = A + (size_t)r * 256 + kq;
  }
  const _Float16* wp[NT];
#pragma unroll
  for (int t = 0; t < NT; ++t)
    wp[t] = W + (size_t)(colbase + t * 16 + m15) * 256 + kq;

  f32x4 acc[4][NT];
#pragma unroll
  for (int rt = 0; rt < 4; ++rt)
#pragma unroll
    for (int t = 0; t < NT; ++t) acc[rt][t] = (f32x4){0.f, 0.f, 0.f, 0.f};

  half8 a0[4], b0[NT], a1[4], b1[NT];
#define LOADSET(AA, BB, KO) \
  { _Pragma("unroll") for (int rt = 0; rt < 4; ++rt) AA[rt] = *(const half8*)(ap[rt] + (KO)); \
    _Pragma("unroll") for (int t = 0; t < NT; ++t)  BB[t]  = *(const half8*)(wp[t] + (KO)); }
#define MFMASET(AA, BB) \
  { _Pragma("unroll") for (int t = 0; t < NT; ++t) \
      _Pragma("unroll") for (int rt = 0; rt < 4; ++rt) \
        acc[rt][t] = __builtin_amdgcn_mfma_f32_16x16x32_f16(AA[rt], BB[t], acc[rt][t], 0, 0, 0); }

  LOADSET(a0, b0, 0)
#pragma unroll 1
  for (int kk = 0; kk < 192; kk += 64) {
    LOADSET(a1, b1, kk + 32)
    MFMASET(a0, b0)
    LOADSET(a0, b0, kk + 64)
    MFMASET(a1, b1)
  }
  LOADSET(a1, b1, 224)
  MFMASET(a0, b0)
  MFMASET(a1, b1)
#undef LOADSET
#undef MFMASET

#pragma unroll
  for (int rt = 0; rt < 4; ++rt) {
    const int orow = rowbase + rt * 16 + quad * 4;
#pragma unroll
    for (int t = 0; t < NT; ++t) {
      const int col = colbase + t * 16 + m15;
      const float bv = bias[col];
#pragma unroll
      for (int i = 0; i < 4; ++i) {
        const int r = orow + i;
        if (r < LQ) out[(size_t)r * 256 + col] = acc[rt][t][i] + bv;
      }
    }
  }
}

// ---- sampler: 8 queries/block, thread = (query, 16 channels) ----
// No per-cam skip: vis folded into weights so all blocks sweep cams in
// lockstep -> per-cam working set (~3 MB) stays L2-resident per XCD.
__global__ __launch_bounds__(128) void sampler(
    const _Float16* __restrict__ vp,     // (6, 5800, 256) f16
    const _Float16* __restrict__ qproj,  // (LQ, 256) f16: [off128, attn64, x]
    const float* __restrict__ ref,       // f32 (6, 1, LQ, 4, 2)
    const int* __restrict__ bev,         // int32 (6, 1, LQ, 4)
    _Float16* __restrict__ slots)        // (LQ, 256) f16 (aliases qproj)
{
  const int t  = threadIdx.x;
  const int ql = t >> 4;
  const int s  = t & 15;
  const int h  = s >> 1;
  const int q  = blockIdx.x * 8 + ql;
  const bool qok = q < LQ;

  __shared__ float s_off[8][8][17];  // [ql][h][p*2+c], padded
  __shared__ float s_w8[8][8][9];    // [ql][h][p], padded
  __shared__ float s_ref[8][48];     // [ql][cam*8 + z*2 + c]
  __shared__ float s_vis[8][6];

  if (s < 6) s_vis[ql][s] = 0.f;
  if (qok) {
    const _Float16* qp = qproj + (size_t)q * 256;
    {
      half8 oc = *(const half8*)(qp + s * 8);
#pragma unroll
      for (int i = 0; i < 8; ++i) {
        const int f = s * 8 + i;
        s_off[ql][f >> 4][f & 15] =
            (float)oc[i] * ((f & 1) ? (1.f / 58.f) : (1.f / 100.f));
      }
    }
    if (s < 8) {  // softmax for head s
      half8 aw = *(const half8*)(qp + 128 + s * 8);
      float m = -1e30f;
#pragma unroll
      for (int p = 0; p < 8; ++p) m = fmaxf(m, (float)aw[p]);
      float e[8], ssum = 0.f;
#pragma unroll
      for (int p = 0; p < 8; ++p) { e[p] = __expf((float)aw[p] - m); ssum += e[p]; }
      const float inv = 1.f / ssum;
#pragma unroll
      for (int p = 0; p < 8; ++p) s_w8[ql][s][p] = e[p] * inv;
    }
    if (s < 12) {
      const int cam = s >> 1, hf = s & 1;
      f32x4 r = *(const f32x4*)(ref + ((size_t)cam * LQ + q) * 8 + hf * 4);
      *(f32x4*)&s_ref[ql][s * 4] = r;
    }
    if (s < 6) {
      int4 bm = *(const int4*)(bev + ((size_t)s * LQ + q) * 4);
      s_vis[ql][s] = (bm.x + bm.y + bm.z + bm.w) > 0 ? 1.f : 0.f;
    }
  }
  __syncthreads();
  if (!qok) return;

  float cnt = 0.f;
#pragma unroll
  for (int c = 0; c < 6; ++c) cnt += s_vis[ql][c];
  const float invc = 1.f / fmaxf(cnt, 1.f);

  float w8r[8];
#pragma unroll
  for (int p = 0; p < 8; ++p) w8r[p] = s_w8[ql][h][p];

  float acc[16];
#pragma unroll
  for (int i = 0; i < 16; ++i) acc[i] = 0.f;

#pragma unroll 1
  for (int cam = 0; cam < NCAMS; ++cam) {
    const float visf = s_vis[ql][cam];
    const _Float16* vpc = vp + (size_t)cam * (S_TOT * CDIM) + s * 16;
    float cx[4], cy[4];
#pragma unroll
    for (int z = 0; z < 4; ++z) {
      cx[z] = s_ref[ql][cam * 8 + z * 2 + 0];
      cy[z] = s_ref[ql][cam * 8 + z * 2 + 1];
    }
#pragma unroll
    for (int p = 0; p < 8; ++p) {
      const int z = p & 3;
      const float x = (cx[z] + s_off[ql][h][p * 2 + 0]) * 100.f - 0.5f;
      const float y = (cy[z] + s_off[ql][h][p * 2 + 1]) * 58.f - 0.5f;
      const float x0f = floorf(x), y0f = floorf(y);
      const float fx = x - x0f, fy = y - y0f;
      const int x0 = (int)x0f, y0 = (int)y0f;
      const float vx0 = (x0 >= 0 && x0 < SPA_W) ? 1.f : 0.f;
      const float vx1 = (x0 >= -1 && x0 < SPA_W - 1) ? 1.f : 0.f;
      const float vy0 = (y0 >= 0 && y0 < SPA_H) ? 1.f : 0.f;
      const float vy1 = (y0 >= -1 && y0 < SPA_H - 1) ? 1.f : 0.f;
      const int xc0 = min(max(x0, 0), SPA_W - 1), xc1 = min(max(x0 + 1, 0), SPA_W - 1);
      const int yc0 = min(max(y0, 0), SPA_H - 1), yc1 = min(max(y0 + 1, 0), SPA_H - 1);
      const float wgt = w8r[p] * visf;
      const float wy0 = (1.f - fy) * vy0 * wgt, wy1 = fy * vy1 * wgt;
      const float bx0 = (1.f - fx) * vx0,       bx1 = fx * vx1;
      const float w00 = wy0 * bx0, w01 = wy0 * bx1;
      const float w10 = wy1 * bx0, w11 = wy1 * bx1;
      const _Float16* t00 = vpc + (size_t)(yc0 * SPA_W + xc0) * CDIM;
      const _Float16* t01 = vpc + (size_t)(yc0 * SPA_W + xc1) * CDIM;
      const _Float16* t10 = vpc + (size_t)(yc1 * SPA_W + xc0) * CDIM;
      const _Float16* t11 = vpc + (size_t)(yc1 * SPA_W + xc1) * CDIM;
      half8 v00a = *(const half8*)t00, v00b = *(const half8*)(t00 + 8);
      half8 v01a = *(const half8*)t01, v01b = *(const half8*)(t01 + 8);
      half8 v10a = *(const half8*)t10, v10b = *(const half8*)(t10 + 8);
      half8 v11a = *(const half8*)t11, v11b = *(const half8*)(t11 + 8);
#pragma unroll
      for (int i = 0; i < 8; ++i) {
        acc[i]     = fmaf(w00, (float)v00a[i], acc[i]);
        acc[8 + i] = fmaf(w00, (float)v00b[i], acc[8 + i]);
        acc[i]     = fmaf(w01, (float)v01a[i], acc[i]);
        acc[8 + i] = fmaf(w01, (float)v01b[i], acc[8 + i]);
        acc[i]     = fmaf(w10, (float)v10a[i], acc[i]);
        acc[8 + i] = fmaf(w10, (float)v10b[i], acc[8 + i]);
        acc[i]     = fmaf(w11, (float)v11a[i], acc[i]);
        acc[8 + i] = fmaf(w11, (float)v11b[i], acc[8 + i]);
      }
    }
  }

  half8 o0, o1;
#pragma unroll
  for (int i = 0; i < 8; ++i) {
    o0[i] = (_Float16)(acc[i] * invc);
    o1[i] = (_Float16)(acc[8 + i] * invc);
  }
  _Float16* sp = slots + (size_t)q * 256 + s * 16;
  *(half8*)sp = o0;
  *(half8*)(sp + 8) = o1;
}

extern "C" void kernel_launch(void* const* d_in, const int* in_sizes, int n_in,
                              void* d_out, int out_size, void* d_ws, size_t ws_size,
                              hipStream_t stream) {
  const float* query  = (const float*)d_in[0];
  const float* refpts = (const float*)d_in[1];
  const int*   bev    = (const int*)d_in[2];
  const float* value  = (const float*)d_in[3];
  const float* W_off  = (const float*)d_in[4];
  const float* b_off  = (const float*)d_in[5];
  const float* W_attn = (const float*)d_in[6];
  const float* b_attn = (const float*)d_in[7];
  const float* W_val  = (const float*)d_in[8];
  const float* b_val  = (const float*)d_in[9];
  const float* W_out  = (const float*)d_in[10];
  const float* b_out  = (const float*)d_in[11];

  char* ws = (char*)d_ws;
  _Float16* vp    = (_Float16*)(ws + 0);          // 17,817,600 B
  _Float16* qproj = (_Float16*)(ws + 17817600);   // 11,520,000 B (stride 256; also slots)
  _Float16* Wv    = (_Float16*)(ws + 29337600);   //    131,072 B
  _Float16* Wcat  = (_Float16*)(ws + 29468672);   //     98,304 B
  _Float16* Wo    = (_Float16*)(ws + 29566976);   //    131,072 B -> end 29,698,048

  cvt_w<<<176, 256, 0, stream>>>(W_val, W_off, W_attn, W_out, Wv, Wcat, Wo);

  gemm_inputs<<<896, 256, 0, stream>>>(value, query, Wv, Wcat,
                                       b_val, b_off, b_attn, vp, qproj);

  sampler<<<(LQ + 7) / 8, 128, 0, stream>>>(vp, qproj, refpts, bev, qproj);

  gemm_out_k<<<(LQ + 63) / 64, 256, 0, stream>>>(qproj, Wo, b_out, (float*)d_out);
}

// Round 7
// 450.490 us; speedup vs baseline: 1.0443x; 1.0443x over previous
//
#include <hip/hip_runtime.h>

#define LQ     22500
#define SPA_H  58
#define SPA_W  100
#define S_TOT  5800
#define NCAMS  6
#define CDIM   256

typedef __attribute__((ext_vector_type(8))) _Float16 half8;
typedef __attribute__((ext_vector_type(4))) _Float16 half4;
typedef __attribute__((ext_vector_type(2))) _Float16 half2v;
typedef __attribute__((ext_vector_type(4))) float f32x4;

__device__ __forceinline__ half8 cvt8(f32x4 lo, f32x4 hi) {
  half8 r;
  r[0] = (_Float16)lo.x; r[1] = (_Float16)lo.y; r[2] = (_Float16)lo.z; r[3] = (_Float16)lo.w;
  r[4] = (_Float16)hi.x; r[5] = (_Float16)hi.y; r[6] = (_Float16)hi.z; r[7] = (_Float16)hi.w;
  return r;
}

// ---- tiny weight conversion: W_val | W_off | W_attn | W_out -> f16 in ws ----
__global__ __launch_bounds__(256) void cvt_w(
    const float* __restrict__ W_val, const float* __restrict__ W_off,
    const float* __restrict__ W_attn, const float* __restrict__ W_out,
    _Float16* __restrict__ Wv, _Float16* __restrict__ Wcat,
    _Float16* __restrict__ Wo) {
  const int e = (blockIdx.x * 256 + threadIdx.x) * 4;
  const float* src; _Float16* dst; int off;
  if (e < 65536)       { src = W_val;  dst = Wv;   off = e; }
  else if (e < 98304)  { src = W_off;  dst = Wcat; off = e - 65536; }
  else if (e < 114688) { src = W_attn; dst = Wcat + 32768; off = e - 98304; }
  else if (e < 180224) { src = W_out;  dst = Wo;   off = e - 114688; }
  else return;
  f32x4 v = *(const f32x4*)(src + off);
  half4 o;
  o[0] = (_Float16)v.x; o[1] = (_Float16)v.y; o[2] = (_Float16)v.z; o[3] = (_Float16)v.w;
  *(half4*)(dst + off) = o;
}

// ---- GEMM, A = f32 (inline cvt): C[M x N] = A[M x 256] @ W[N x 256]^T + b --
template<int N>
__device__ __forceinline__ void gemm_body_af32(
    const float* __restrict__ A, const _Float16* __restrict__ W,
    const float* __restrict__ bias, const float* __restrict__ bias2,
    _Float16* __restrict__ C, int M, int rowbase) {
  constexpr int NT = N / 64;
  const int lane = threadIdx.x & 63;
  const int wave = threadIdx.x >> 6;
  const int m15  = lane & 15;
  const int quad = lane >> 4;
  const int colbase = wave * (N / 4);
  const int kq = quad * 8;

  const float* ap[4];
#pragma unroll
  for (int rt = 0; rt < 4; ++rt) {
    int r = rowbase + rt * 16 + m15;
    r = r < M ? r : M - 1;
    ap[rt] = A + (size_t)r * 256 + kq;
  }
  const _Float16* wp[NT];
#pragma unroll
  for (int t = 0; t < NT; ++t)
    wp[t] = W + (size_t)(colbase + t * 16 + m15) * 256 + kq;

  f32x4 acc[4][NT];
#pragma unroll
  for (int rt = 0; rt < 4; ++rt)
#pragma unroll
    for (int t = 0; t < NT; ++t) acc[rt][t] = (f32x4){0.f, 0.f, 0.f, 0.f};

  f32x4 al0[4], ah0[4], al1[4], ah1[4];
  half8 b0[NT], b1[NT];

#define LOADSET(AL, AH, BB, KO) \
  { _Pragma("unroll") for (int rt = 0; rt < 4; ++rt) { \
      AL[rt] = *(const f32x4*)(ap[rt] + (KO)); \
      AH[rt] = *(const f32x4*)(ap[rt] + (KO) + 4); } \
    _Pragma("unroll") for (int t = 0; t < NT; ++t) \
      BB[t] = *(const half8*)(wp[t] + (KO)); }
#define MFMASET(AL, AH, BB) \
  { half8 af[4]; \
    _Pragma("unroll") for (int rt = 0; rt < 4; ++rt) af[rt] = cvt8(AL[rt], AH[rt]); \
    _Pragma("unroll") for (int t = 0; t < NT; ++t) \
      _Pragma("unroll") for (int rt = 0; rt < 4; ++rt) \
        acc[rt][t] = __builtin_amdgcn_mfma_f32_16x16x32_f16(af[rt], BB[t], acc[rt][t], 0, 0, 0); }

  LOADSET(al0, ah0, b0, 0)
#pragma unroll 1
  for (int kk = 0; kk < 192; kk += 64) {
    LOADSET(al1, ah1, b1, kk + 32)
    MFMASET(al0, ah0, b0)
    LOADSET(al0, ah0, b0, kk + 64)
    MFMASET(al1, ah1, b1)
  }
  LOADSET(al1, ah1, b1, 224)
  MFMASET(al0, ah0, b0)
  MFMASET(al1, ah1, b1)
#undef LOADSET
#undef MFMASET

#pragma unroll
  for (int rt = 0; rt < 4; ++rt) {
    const int orow = rowbase + rt * 16 + quad * 4;
#pragma unroll
    for (int t = 0; t < NT; ++t) {
      const int col = colbase + t * 16 + m15;
      const float bv = (N == 192 && col >= 128) ? bias2[col - 128] : bias[col];
#pragma unroll
      for (int i = 0; i < 4; ++i) {
        const int r = orow + i;
        if (r < M) C[(size_t)r * 256 + col] = (_Float16)(acc[rt][t][i] + bv);
      }
    }
  }
}

// blocks [0,544): value-proj (N=256). [544,896): query-proj (N=192).
__global__ __launch_bounds__(256, 2) void gemm_inputs(
    const float* __restrict__ value, const float* __restrict__ query,
    const _Float16* __restrict__ Wv, const _Float16* __restrict__ Wcat,
    const float* __restrict__ b_val, const float* __restrict__ b_off,
    const float* __restrict__ b_attn,
    _Float16* __restrict__ vp, _Float16* __restrict__ qproj) {
  const int b = blockIdx.x;
  if (b < 544) gemm_body_af32<256>(value, Wv, b_val, b_val, vp, 34800, b * 64);
  else         gemm_body_af32<192>(query, Wcat, b_off, b_attn, qproj, LQ, (b - 544) * 64);
}

// ---- fused sampler + output projection ----
// Block = 256 thr = 8 queries x 32 lanes (8 channels each).
// Phase 1: deformable gather (dot2 accumulate, vis folded, no cam skip).
// Phase 2: slots -> LDS, MFMA x W_out -> f32 d_out.
__global__ __launch_bounds__(256) void sampler_fused(
    const _Float16* __restrict__ vp,     // (6, 5800, 256) f16
    const _Float16* __restrict__ qproj,  // (LQ, 256) f16: [off128, attn64, x64]
    const float* __restrict__ ref,       // f32 (6, 1, LQ, 4, 2)
    const int* __restrict__ bev,         // int32 (6, 1, LQ, 4)
    const _Float16* __restrict__ Wo,     // (256, 256) f16
    const float* __restrict__ b_out,     // f32 (256)
    float* __restrict__ out)             // (LQ, 256) f32
{
  const int t  = threadIdx.x;
  const int ql = t >> 5;        // query slot 0..7
  const int s  = t & 31;        // 32 lanes per query
  const int h  = s >> 2;        // head 0..7 (4 lanes per head)
  const int q0 = blockIdx.x * 8;
  const int q  = q0 + ql;
  const bool qok = q < LQ;

  __shared__ float s_off[8][8][17];     // [ql][h][p*2+c] padded
  __shared__ float s_w8[8][8][9];       // [ql][h][p] padded
  __shared__ float s_ref[8][48];        // [ql][cam*8 + z*2 + c]
  __shared__ float s_vis[8][6];
  __shared__ _Float16 s_slots[16][264]; // rows 8..15 stay zero (M-pad)

  // zero the slot tile (covers q-tail and zero-pad rows)
  {
    half8 z = {};
    _Float16* sl = &s_slots[0][0];
#pragma unroll
    for (int rep = 0; rep < 3; ++rep) {
      const int idx = t + rep * 256;
      if (idx < 528) *(half8*)(sl + idx * 8) = z;
    }
  }

  if (qok) {
    if (s < 24) {
      half8 qc = *(const half8*)(qproj + (size_t)q * 256 + s * 8);
      if (s < 16) {
#pragma unroll
        for (int i = 0; i < 8; ++i) {
          const int f = s * 8 + i;
          s_off[ql][f >> 4][f & 15] =
              (float)qc[i] * ((f & 1) ? (1.f / 58.f) : (1.f / 100.f));
        }
      } else {
        const int hh = s - 16;   // softmax for head hh
        float m = -1e30f;
#pragma unroll
        for (int p = 0; p < 8; ++p) m = fmaxf(m, (float)qc[p]);
        float e[8], ssum = 0.f;
#pragma unroll
        for (int p = 0; p < 8; ++p) { e[p] = __expf((float)qc[p] - m); ssum += e[p]; }
        const float inv = 1.f / ssum;
#pragma unroll
        for (int p = 0; p < 8; ++p) s_w8[ql][hh][p] = e[p] * inv;
      }
    }
    if (s < 12) {
      const int cam = s >> 1, half = s & 1;
      f32x4 r = *(const f32x4*)(ref + ((size_t)cam * LQ + q) * 8 + half * 4);
      *(f32x4*)&s_ref[ql][s * 4] = r;
    }
    if (s < 6) {
      int4 bm = *(const int4*)(bev + ((size_t)s * LQ + q) * 4);
      s_vis[ql][s] = (bm.x + bm.y + bm.z + bm.w) > 0 ? 1.f : 0.f;
    }
  }
  __syncthreads();

  float acc[8];
#pragma unroll
  for (int i = 0; i < 8; ++i) acc[i] = 0.f;

  if (qok) {
    float cnt = 0.f;
#pragma unroll
    for (int c = 0; c < 6; ++c) cnt += s_vis[ql][c];
    const float invc = 1.f / fmaxf(cnt, 1.f);

#pragma unroll 1
    for (int cam = 0; cam < NCAMS; ++cam) {
      const float visf = s_vis[ql][cam];
      const _Float16* vpc = vp + (size_t)cam * (S_TOT * CDIM) + s * 8;
#pragma unroll 2
      for (int p = 0; p < 8; ++p) {
        const int z = p & 3;
        const float x = (s_ref[ql][cam * 8 + z * 2 + 0] + s_off[ql][h][p * 2 + 0]) * 100.f - 0.5f;
        const float y = (s_ref[ql][cam * 8 + z * 2 + 1] + s_off[ql][h][p * 2 + 1]) * 58.f - 0.5f;
        const float x0f = floorf(x), y0f = floorf(y);
        const float fx = x - x0f, fy = y - y0f;
        const int x0 = (int)x0f, y0 = (int)y0f;
        const float vx0 = (x0 >= 0 && x0 < SPA_W) ? 1.f : 0.f;
        const float vx1 = (x0 >= -1 && x0 < SPA_W - 1) ? 1.f : 0.f;
        const float vy0 = (y0 >= 0 && y0 < SPA_H) ? 1.f : 0.f;
        const float vy1 = (y0 >= -1 && y0 < SPA_H - 1) ? 1.f : 0.f;
        const int xc0 = min(max(x0, 0), SPA_W - 1), xc1 = min(max(x0 + 1, 0), SPA_W - 1);
        const int yc0 = min(max(y0, 0), SPA_H - 1), yc1 = min(max(y0 + 1, 0), SPA_H - 1);
        const float wgt = s_w8[ql][h][p] * visf;
        const float wy0 = (1.f - fy) * vy0 * wgt, wy1 = fy * vy1 * wgt;
        const float bx0 = (1.f - fx) * vx0,       bx1 = fx * vx1;
        const float w00 = wy0 * bx0, w01 = wy0 * bx1;
        const float w10 = wy1 * bx0, w11 = wy1 * bx1;
        half8 v00 = *(const half8*)(vpc + (size_t)(yc0 * SPA_W + xc0) * CDIM);
        half8 v01 = *(const half8*)(vpc + (size_t)(yc0 * SPA_W + xc1) * CDIM);
        half8 v10 = *(const half8*)(vpc + (size_t)(yc1 * SPA_W + xc0) * CDIM);
        half8 v11 = *(const half8*)(vpc + (size_t)(yc1 * SPA_W + xc1) * CDIM);
#if __has_builtin(__builtin_amdgcn_fdot2)
        half2v wa; wa[0] = (_Float16)w00; wa[1] = (_Float16)w01;
        half2v wb; wb[0] = (_Float16)w10; wb[1] = (_Float16)w11;
#pragma unroll
        for (int i = 0; i < 8; ++i) {
          half2v va; va[0] = v00[i]; va[1] = v01[i];
          half2v vb; vb[0] = v10[i]; vb[1] = v11[i];
          acc[i] = __builtin_amdgcn_fdot2(va, wa, acc[i], false);
          acc[i] = __builtin_amdgcn_fdot2(vb, wb, acc[i], false);
        }
#else
#pragma unroll
        for (int i = 0; i < 8; ++i) {
          acc[i] = fmaf(w00, (float)v00[i], acc[i]);
          acc[i] = fmaf(w01, (float)v01[i], acc[i]);
          acc[i] = fmaf(w10, (float)v10[i], acc[i]);
          acc[i] = fmaf(w11, (float)v11[i], acc[i]);
        }
#endif
      }
    }

    half8 o;
#pragma unroll
    for (int i = 0; i < 8; ++i) o[i] = (_Float16)(acc[i] * invc);
    *(half8*)(&s_slots[ql][s * 8]) = o;
  }
  __syncthreads();

  // ---- phase 2: out[q0..q0+7][:] = slots @ Wo^T + b_out via MFMA ----
  const int lane = t & 63;
  const int wave = t >> 6;
  const int m15  = lane & 15;
  const int quad = lane >> 4;
  const int colbase = wave * 64;

  f32x4 acc4[4];
#pragma unroll
  for (int tt = 0; tt < 4; ++tt) acc4[tt] = (f32x4){0.f, 0.f, 0.f, 0.f};

  const _Float16* arow = &s_slots[m15][quad * 8];
  const _Float16* wp[4];
#pragma unroll
  for (int tt = 0; tt < 4; ++tt)
    wp[tt] = Wo + (size_t)(colbase + tt * 16 + m15) * 256 + quad * 8;

#pragma unroll 2
  for (int kk = 0; kk < 256; kk += 32) {
    half8 a = *(const half8*)(arow + kk);
#pragma unroll
    for (int tt = 0; tt < 4; ++tt) {
      half8 b = *(const half8*)(wp[tt] + kk);
      acc4[tt] = __builtin_amdgcn_mfma_f32_16x16x32_f16(a, b, acc4[tt], 0, 0, 0);
    }
  }

#pragma unroll
  for (int tt = 0; tt < 4; ++tt) {
    const int col = colbase + tt * 16 + m15;
    const float bv = b_out[col];
#pragma unroll
    for (int i = 0; i < 4; ++i) {
      const int row = quad * 4 + i;
      if (row < 8 && q0 + row < LQ)
        out[(size_t)(q0 + row) * 256 + col] = acc4[tt][i] + bv;
    }
  }
}

extern "C" void kernel_launch(void* const* d_in, const int* in_sizes, int n_in,
                              void* d_out, int out_size, void* d_ws, size_t ws_size,
                              hipStream_t stream) {
  const float* query  = (const float*)d_in[0];
  const float* refpts = (const float*)d_in[1];
  const int*   bev    = (const int*)d_in[2];
  const float* value  = (const float*)d_in[3];
  const float* W_off  = (const float*)d_in[4];
  const float* b_off  = (const float*)d_in[5];
  const float* W_attn = (const float*)d_in[6];
  const float* b_attn = (const float*)d_in[7];
  const float* W_val  = (const float*)d_in[8];
  const float* b_val  = (const float*)d_in[9];
  const float* W_out  = (const float*)d_in[10];
  const float* b_out  = (const float*)d_in[11];

  char* ws = (char*)d_ws;
  _Float16* vp    = (_Float16*)(ws + 0);          // 17,817,600 B
  _Float16* qproj = (_Float16*)(ws + 17817600);   // 11,520,000 B (stride 256)
  _Float16* Wv    = (_Float16*)(ws + 29337600);   //    131,072 B
  _Float16* Wcat  = (_Float16*)(ws + 29468672);   //     98,304 B
  _Float16* Wo    = (_Float16*)(ws + 29566976);   //    131,072 B -> end 29,698,048

  cvt_w<<<176, 256, 0, stream>>>(W_val, W_off, W_attn, W_out, Wv, Wcat, Wo);

  gemm_inputs<<<896, 256, 0, stream>>>(value, query, Wv, Wcat,
                                       b_val, b_off, b_attn, vp, qproj);

  sampler_fused<<<(LQ + 7) / 8, 256, 0, stream>>>(vp, qproj, refpts, bev,
                                                  Wo, b_out, (float*)d_out);
}